// Round 8
// baseline (60.172 us; speedup 1.0000x reference)
//
#include <hip/hip_runtime.h>
#include <math.h>

#define BN 256
#define BLOCK 512

template<int P, int Q>
__device__ __forceinline__ void jrot(float K[3][3], float V[3][3]) {
  float apq = K[P][Q];
  if (apq == 0.f) return;
  float app = K[P][P], aqq = K[Q][Q];
  float tau = (aqq - app) / (2.f * apq);
  float st = sqrtf(1.f + tau * tau);
  float tt = (tau >= 0.f) ? 1.f / (tau + st) : 1.f / (tau - st);
  float c = 1.f / sqrtf(1.f + tt * tt);
  float s = tt * c;
#pragma unroll
  for (int k = 0; k < 3; k++) { float kp = K[k][P], kq = K[k][Q]; K[k][P] = c * kp - s * kq; K[k][Q] = s * kp + c * kq; }
#pragma unroll
  for (int k = 0; k < 3; k++) { float kp = K[P][k], kq = K[Q][k]; K[P][k] = c * kp - s * kq; K[Q][k] = s * kp + c * kq; }
#pragma unroll
  for (int k = 0; k < 3; k++) { float vp = V[k][P], vq = V[k][Q]; V[k][P] = c * vp - s * vq; V[k][Q] = s * vp + c * vq; }
}

template<int A, int C>
__device__ __forceinline__ void cswap(float lam[3], float V[3][3]) {
  if (lam[A] < lam[C]) {
    float tl = lam[A]; lam[A] = lam[C]; lam[C] = tl;
#pragma unroll
    for (int k = 0; k < 3; k++) { float tv = V[k][A]; V[k][A] = V[k][C]; V[k][C] = tv; }
  }
}

__device__ __forceinline__ void acc4(float4& T, float s, const float4& e) {
  T.x += s * e.x; T.y += s * e.y; T.z += s * e.z; T.w += s * e.w;
}

__device__ __forceinline__ float dot4(const float4& a, const float4& b) {
  return a.x * b.x + a.y * b.y + a.z * b.z + a.w * b.w;
}

extern "C" __global__ void __launch_bounds__(BLOCK, 2)
svdhead_kernel(const float* __restrict__ src,
               const float* __restrict__ tgt,
               const float* __restrict__ scores,
               const int* __restrict__ idx0,
               float* __restrict__ out)
{
  __shared__ __align__(16) float Af[6][BN];   // [0..2]=count*kpts1_d, [3..5]=kpts1_d
  __shared__ __align__(16) float kxv[BN][4];  // {x0, x1, x2, vf} per row
  __shared__ int cnt[BN];
  __shared__ float bacc[31];  // 0..8 P_v, 9..17 P_f, 18..20 Sc, 21..23 Scf, 24..26 Sxv, 27..29 Sxf, 30 M

  const int t = threadIdx.x;
  const int b = blockIdx.x;
  const int lane = t & 63;

  if (t < 31) bacc[t] = 0.f;
  if (t < BN) cnt[t] = 0;
  __syncthreads();

  float x0 = 0.f, x1 = 0.f, x2 = 0.f, vf = 0.f;
  if (t < BN) {
    int id = idx0[(size_t)b * BN + t];        // values in [0,256]; 256 == SENTINEL
    int valid = ((unsigned)id < 256u);
    vf = valid ? 1.f : 0.f;
    if (valid) atomicAdd(&cnt[id], 1);
    const float* sb = src + (size_t)b * 3 * BN;
    const float* tb = tgt + (size_t)b * 3 * BN;
    x0 = sb[t]; x1 = sb[BN + t]; x2 = sb[2 * BN + t];
    kxv[t][0] = x0; kxv[t][1] = x1; kxv[t][2] = x2; kxv[t][3] = vf;
    Af[3][t] = tb[t]; Af[4][t] = tb[BN + t]; Af[5][t] = tb[2 * BN + t];
  }
  {
    // stage-interleaved 7-value butterfly (ILP-7 on the DS chain)
    float rr[7];
    rr[0] = vf; rr[1] = vf * x0; rr[2] = vf * x1; rr[3] = vf * x2;
    rr[4] = x0; rr[5] = x1; rr[6] = x2;
#pragma unroll
    for (int m = 32; m >= 1; m >>= 1) {
#pragma unroll
      for (int k = 0; k < 7; k++) rr[k] += __shfl_xor(rr[k], m, 64);
    }
    if (lane == 0) {
      atomicAdd(&bacc[30], rr[0]);
      atomicAdd(&bacc[24], rr[1]); atomicAdd(&bacc[25], rr[2]); atomicAdd(&bacc[26], rr[3]);
      atomicAdd(&bacc[27], rr[4]); atomicAdd(&bacc[28], rr[5]); atomicAdd(&bacc[29], rr[6]);
    }
  }
  __syncthreads();
  if (t < BN) {
    float cf = (float)cnt[t];
    Af[0][t] = cf * Af[3][t];
    Af[1][t] = cf * Af[4][t];
    Af[2][t] = cf * Af[5][t];
  }
  __syncthreads();

  const int j0 = lane * 4;
  const int wave = t >> 6;
  const float* srow = scores + (size_t)b * BN * BN;
  const int pbase = wave * 32;                 // 32 rows per wave, 8 per batch
  const float* wbase = srow + (size_t)pbase * BN + j0;

  // per-lane column accumulators
  float4 Tv0 = {0,0,0,0}, Tv1 = {0,0,0,0}, Tv2 = {0,0,0,0}, Tv3 = {0,0,0,0};
  float4 Tf0 = {0,0,0,0}, Tf1 = {0,0,0,0}, Tf2 = {0,0,0,0}, Tf3 = {0,0,0,0};

  float4 cur[8];
#pragma unroll
  for (int r = 0; r < 8; r++) cur[r] = *(const float4*)(wbase + (size_t)r * BN);

#pragma unroll 1
  for (int g = 0; g < 4; g++) {
    const int gn = (g < 3) ? (g + 1) : 3;     // clamp: last iter re-loads (cache hit)
    float4 nx[8];
#pragma unroll
    for (int r = 0; r < 8; r++)
      nx[r] = *(const float4*)(wbase + (size_t)(8 * gn + r) * BN);
    // pin the prefetch loads before the compute phase
    __builtin_amdgcn_sched_barrier(0);

    // exp in place + per-lane partial sums
    float s[8];
#pragma unroll
    for (int r = 0; r < 8; r++) {
      cur[r].x = __expf(cur[r].x); cur[r].y = __expf(cur[r].y);
      cur[r].z = __expf(cur[r].z); cur[r].w = __expf(cur[r].w);
      s[r] = (cur[r].x + cur[r].y) + (cur[r].z + cur[r].w);
    }
    // 8 interleaved 64-lane butterflies (ILP-8 on the DS chain)
#pragma unroll
    for (int m = 32; m >= 1; m >>= 1) {
#pragma unroll
      for (int r = 0; r < 8; r++) s[r] += __shfl_xor(s[r], m, 64);
    }
#pragma unroll
    for (int r = 0; r < 8; r++) {
      float inv = __builtin_amdgcn_rcpf(s[r]);
      float4 kv = *(const float4*)&kxv[pbase + 8 * g + r][0];
      float wf1 = inv * kv.x, wf2 = inv * kv.y, wf3 = inv * kv.z;
      float wv0 = kv.w * inv;
      float wv1 = kv.w * wf1, wv2 = kv.w * wf2, wv3 = kv.w * wf3;
      acc4(Tf0, inv, cur[r]);
      acc4(Tf1, wf1, cur[r]);
      acc4(Tf2, wf2, cur[r]);
      acc4(Tf3, wf3, cur[r]);
      acc4(Tv0, wv0, cur[r]);
      acc4(Tv1, wv1, cur[r]);
      acc4(Tv2, wv2, cur[r]);
      acc4(Tv3, wv3, cur[r]);
    }
#pragma unroll
    for (int r = 0; r < 8; r++) cur[r] = nx[r];
  }

  // epilogue dots: contract T accumulators with the A columns this lane owns
  float acc[24];
  {
    float4 a6[6];
#pragma unroll
    for (int k = 0; k < 6; k++) a6[k] = *(const float4*)&Af[k][j0];
#pragma unroll
    for (int e = 0; e < 3; e++) {
      acc[0 + e]  = dot4(Tv1, a6[e]);      // P_v row d=0
      acc[3 + e]  = dot4(Tv2, a6[e]);      // P_v row d=1
      acc[6 + e]  = dot4(Tv3, a6[e]);      // P_v row d=2
      acc[9 + e]  = dot4(Tf1, a6[3 + e]);  // P_f row d=0
      acc[12 + e] = dot4(Tf2, a6[3 + e]);  // P_f row d=1
      acc[15 + e] = dot4(Tf3, a6[3 + e]);  // P_f row d=2
      acc[18 + e] = dot4(Tv0, a6[e]);      // Sc
      acc[21 + e] = dot4(Tf0, a6[3 + e]);  // Scf
    }
  }
  // stage-interleaved 24-value butterfly (ILP-24 on the DS chain)
#pragma unroll
  for (int m = 32; m >= 1; m >>= 1) {
#pragma unroll
    for (int k = 0; k < 24; k++) acc[k] += __shfl_xor(acc[k], m, 64);
  }
  if (lane == 0) {
#pragma unroll
    for (int k = 0; k < 24; k++) atomicAdd(&bacc[k], acc[k]);
  }
  __syncthreads();

  if (t == 0) {
    float M = bacc[30];
    float Minv = 1.f / fmaxf(M, 1.f);
    bool use_v = (M > 3.f);
    const float Ninv = 1.f / (float)BN;
    float H[3][3], mu[3];
#pragma unroll
    for (int d = 0; d < 3; d++) {
      mu[d] = use_v ? bacc[24 + d] * Minv : bacc[27 + d] * Ninv;
#pragma unroll
      for (int e = 0; e < 3; e++) {
        float hv = bacc[d * 3 + e]     - bacc[24 + d] * bacc[18 + e] * Minv;
        float hf = bacc[9 + d * 3 + e] - bacc[27 + d] * bacc[21 + e] * Ninv;
        H[d][e] = use_v ? hv : hf;
      }
    }
    float K[3][3];
#pragma unroll
    for (int i = 0; i < 3; i++)
#pragma unroll
      for (int j = 0; j < 3; j++) {
        float s_ = 0.f;
#pragma unroll
        for (int k = 0; k < 3; k++) s_ += H[k][i] * H[k][j];
        K[i][j] = s_;
      }
    float V[3][3] = {{1.f,0.f,0.f},{0.f,1.f,0.f},{0.f,0.f,1.f}};
    for (int sw = 0; sw < 8; sw++) { jrot<0,1>(K, V); jrot<0,2>(K, V); jrot<1,2>(K, V); }
    float lam[3] = {K[0][0], K[1][1], K[2][2]};
    cswap<0,1>(lam, V); cswap<1,2>(lam, V); cswap<0,1>(lam, V);

    float v1[3] = {V[0][0], V[1][0], V[2][0]};
    float v2[3] = {V[0][1], V[1][1], V[2][1]};
    float v3[3] = {V[0][2], V[1][2], V[2][2]};
    float u1[3], u2[3], u3[3];
#pragma unroll
    for (int i = 0; i < 3; i++) {
      u1[i] = H[i][0] * v1[0] + H[i][1] * v1[1] + H[i][2] * v1[2];
      u2[i] = H[i][0] * v2[0] + H[i][1] * v2[1] + H[i][2] * v2[2];
    }
    float n1s = u1[0]*u1[0] + u1[1]*u1[1] + u1[2]*u1[2];
    if (n1s > 1e-24f) { float r = 1.f / sqrtf(n1s); u1[0]*=r; u1[1]*=r; u1[2]*=r; }
    else { u1[0] = 1.f; u1[1] = 0.f; u1[2] = 0.f; }
    float d12 = u1[0]*u2[0] + u1[1]*u2[1] + u1[2]*u2[2];
    u2[0] -= d12 * u1[0]; u2[1] -= d12 * u1[1]; u2[2] -= d12 * u1[2];
    float n2s = u2[0]*u2[0] + u2[1]*u2[1] + u2[2]*u2[2];
    if (n2s > 1e-24f) { float r = 1.f / sqrtf(n2s); u2[0]*=r; u2[1]*=r; u2[2]*=r; }
    else {
      float ex_ = (fabsf(u1[0]) < 0.9f) ? 1.f : 0.f;
      float ey = 1.f - ex_;
      float cx = u1[1]*0.f - u1[2]*ey;
      float cy = u1[2]*ex_ - u1[0]*0.f;
      float cz = u1[0]*ey - u1[1]*ex_;
      float nn = 1.f / sqrtf(cx*cx + cy*cy + cz*cz + 1e-30f);
      u2[0] = cx*nn; u2[1] = cy*nn; u2[2] = cz*nn;
    }
    u3[0] = u1[1]*u2[2] - u1[2]*u2[1];
    u3[1] = u1[2]*u2[0] - u1[0]*u2[2];
    u3[2] = u1[0]*u2[1] - u1[1]*u2[0];
    float detV = v1[0]*(v2[1]*v3[2] - v2[2]*v3[1])
               - v1[1]*(v2[0]*v3[2] - v2[2]*v3[0])
               + v1[2]*(v2[0]*v3[1] - v2[1]*v3[0]);
    float f = (detV < 0.f) ? -1.f : 1.f;
    float R_[3][3];
#pragma unroll
    for (int i = 0; i < 3; i++)
#pragma unroll
      for (int k = 0; k < 3; k++)
        R_[i][k] = v1[i]*u1[k] + v2[i]*u2[k] + f * v3[i]*u3[k];

    float* Rout = out + (size_t)b * 9;
#pragma unroll
    for (int i = 0; i < 3; i++)
#pragma unroll
      for (int k = 0; k < 3; k++)
        Rout[i * 3 + k] = R_[i][k];
    float* Tout = out + (size_t)gridDim.x * 9 + (size_t)b * 3;
#pragma unroll
    for (int i = 0; i < 3; i++)
      Tout[i] = -(R_[i][0]*mu[0] + R_[i][1]*mu[1] + R_[i][2]*mu[2]);
  }
}

extern "C" void kernel_launch(void* const* d_in, const int* in_sizes, int n_in,
                              void* d_out, int out_size, void* d_ws, size_t ws_size,
                              hipStream_t stream) {
  const float* src = (const float*)d_in[0];
  const float* tgt = (const float*)d_in[1];
  const float* scores = (const float*)d_in[2];
  const int* idx0 = (const int*)d_in[3];
  float* out = (float*)d_out;
  int B = in_sizes[0] / (3 * BN);
  hipLaunchKernelGGL(svdhead_kernel, dim3(B), dim3(BLOCK), 0, stream,
                     src, tgt, scores, idx0, out);
}

// Round 9
// 52.097 us; speedup vs baseline: 1.1550x; 1.1550x over previous
//
#include <hip/hip_runtime.h>
#include <math.h>

#define BN 256
#define BLOCK 512

// 6-op DPP wave64 sum: result valid in lane 63 (VALU only, no DS pipe)
__device__ __forceinline__ float dpp_red63(float x) {
  x += __int_as_float(__builtin_amdgcn_update_dpp(0, __float_as_int(x), 0x111, 0xf, 0xf, true)); // row_shr:1
  x += __int_as_float(__builtin_amdgcn_update_dpp(0, __float_as_int(x), 0x112, 0xf, 0xf, true)); // row_shr:2
  x += __int_as_float(__builtin_amdgcn_update_dpp(0, __float_as_int(x), 0x114, 0xf, 0xf, true)); // row_shr:4
  x += __int_as_float(__builtin_amdgcn_update_dpp(0, __float_as_int(x), 0x118, 0xf, 0xf, true)); // row_shr:8
  x += __int_as_float(__builtin_amdgcn_update_dpp(0, __float_as_int(x), 0x142, 0xf, 0xf, true)); // row_bcast:15
  x += __int_as_float(__builtin_amdgcn_update_dpp(0, __float_as_int(x), 0x143, 0xf, 0xf, true)); // row_bcast:31
  return x;
}

__device__ __forceinline__ float bcast63(float x) {
  return __int_as_float(__builtin_amdgcn_readlane(__float_as_int(x), 63));
}

template<int P, int Q>
__device__ __forceinline__ void jrot(float K[3][3], float V[3][3]) {
  float apq = K[P][Q];
  if (apq == 0.f) return;
  float app = K[P][P], aqq = K[Q][Q];
  float tau = (aqq - app) / (2.f * apq);
  float st = sqrtf(1.f + tau * tau);
  float tt = (tau >= 0.f) ? 1.f / (tau + st) : 1.f / (tau - st);
  float c = 1.f / sqrtf(1.f + tt * tt);
  float s = tt * c;
#pragma unroll
  for (int k = 0; k < 3; k++) { float kp = K[k][P], kq = K[k][Q]; K[k][P] = c * kp - s * kq; K[k][Q] = s * kp + c * kq; }
#pragma unroll
  for (int k = 0; k < 3; k++) { float kp = K[P][k], kq = K[Q][k]; K[P][k] = c * kp - s * kq; K[Q][k] = s * kp + c * kq; }
#pragma unroll
  for (int k = 0; k < 3; k++) { float vp = V[k][P], vq = V[k][Q]; V[k][P] = c * vp - s * vq; V[k][Q] = s * vp + c * vq; }
}

template<int A, int C>
__device__ __forceinline__ void cswap(float lam[3], float V[3][3]) {
  if (lam[A] < lam[C]) {
    float tl = lam[A]; lam[A] = lam[C]; lam[C] = tl;
#pragma unroll
    for (int k = 0; k < 3; k++) { float tv = V[k][A]; V[k][A] = V[k][C]; V[k][C] = tv; }
  }
}

__device__ __forceinline__ void acc4(float4& T, float s, const float4& e) {
  T.x += s * e.x; T.y += s * e.y; T.z += s * e.z; T.w += s * e.w;
}

__device__ __forceinline__ float dot4(const float4& a, const float4& b) {
  return a.x * b.x + a.y * b.y + a.z * b.z + a.w * b.w;
}

extern "C" __global__ void __launch_bounds__(BLOCK, 2)
svdhead_kernel(const float* __restrict__ src,
               const float* __restrict__ tgt,
               const float* __restrict__ scores,
               const int* __restrict__ idx0,
               float* __restrict__ out)
{
  __shared__ __align__(16) float Af[6][BN];   // [0..2]=count*kpts1_d, [3..5]=kpts1_d
  __shared__ __align__(16) float kxv[BN][4];  // {x0, x1, x2, vf} per row
  __shared__ int cnt[BN];
  __shared__ float bacc[31];  // 0..8 P_v, 9..17 P_f, 18..20 Sc, 21..23 Scf, 24..26 Sxv, 27..29 Sxf, 30 M

  const int t = threadIdx.x;
  const int b = blockIdx.x;
  const int lane = t & 63;

  if (t < 31) bacc[t] = 0.f;
  if (t < BN) cnt[t] = 0;
  __syncthreads();

  float x0 = 0.f, x1 = 0.f, x2 = 0.f, vf = 0.f;
  if (t < BN) {
    int id = idx0[(size_t)b * BN + t];        // values in [0,256]; 256 == SENTINEL
    int valid = ((unsigned)id < 256u);
    vf = valid ? 1.f : 0.f;
    if (valid) atomicAdd(&cnt[id], 1);
    const float* sb = src + (size_t)b * 3 * BN;
    const float* tb = tgt + (size_t)b * 3 * BN;
    x0 = sb[t]; x1 = sb[BN + t]; x2 = sb[2 * BN + t];
    kxv[t][0] = x0; kxv[t][1] = x1; kxv[t][2] = x2; kxv[t][3] = vf;
    Af[3][t] = tb[t]; Af[4][t] = tb[BN + t]; Af[5][t] = tb[2 * BN + t];
  }
  {
    // 7-value DPP reduction (independent chains, VALU only)
    float rr[7];
    rr[0] = vf; rr[1] = vf * x0; rr[2] = vf * x1; rr[3] = vf * x2;
    rr[4] = x0; rr[5] = x1; rr[6] = x2;
#pragma unroll
    for (int k = 0; k < 7; k++) rr[k] = dpp_red63(rr[k]);
    if (lane == 63) {
      atomicAdd(&bacc[30], rr[0]);
      atomicAdd(&bacc[24], rr[1]); atomicAdd(&bacc[25], rr[2]); atomicAdd(&bacc[26], rr[3]);
      atomicAdd(&bacc[27], rr[4]); atomicAdd(&bacc[28], rr[5]); atomicAdd(&bacc[29], rr[6]);
    }
  }
  __syncthreads();
  if (t < BN) {
    float cf = (float)cnt[t];
    Af[0][t] = cf * Af[3][t];
    Af[1][t] = cf * Af[4][t];
    Af[2][t] = cf * Af[5][t];
  }
  __syncthreads();

  const int j0 = lane * 4;
  const int wave = t >> 6;
  const float* srow = scores + (size_t)b * BN * BN;
  const int pbase = wave * 32;                 // 32 rows per wave, 8 per batch
  const float* wbase = srow + (size_t)pbase * BN + j0;

  // per-lane column accumulators
  float4 Tv0 = {0,0,0,0}, Tv1 = {0,0,0,0}, Tv2 = {0,0,0,0}, Tv3 = {0,0,0,0};
  float4 Tf0 = {0,0,0,0}, Tf1 = {0,0,0,0}, Tf2 = {0,0,0,0}, Tf3 = {0,0,0,0};

  float4 cur[8];
#pragma unroll
  for (int r = 0; r < 8; r++) cur[r] = *(const float4*)(wbase + (size_t)r * BN);

#pragma unroll 1
  for (int g = 0; g < 4; g++) {
    const int gn = (g < 3) ? (g + 1) : 3;     // clamp: last iter re-loads (cache hit)
    float4 nx[8];
#pragma unroll
    for (int r = 0; r < 8; r++)
      nx[r] = *(const float4*)(wbase + (size_t)(8 * gn + r) * BN);
    // pin the prefetch loads before the compute phase
    __builtin_amdgcn_sched_barrier(0);

    // exp in place + per-lane partial sums
    float s[8];
#pragma unroll
    for (int r = 0; r < 8; r++) {
      cur[r].x = __expf(cur[r].x); cur[r].y = __expf(cur[r].y);
      cur[r].z = __expf(cur[r].z); cur[r].w = __expf(cur[r].w);
      s[r] = (cur[r].x + cur[r].y) + (cur[r].z + cur[r].w);
    }
    // 8 independent DPP reduction chains (VALU pipe, no DS)
#pragma unroll
    for (int r = 0; r < 8; r++) s[r] = dpp_red63(s[r]);
#pragma unroll
    for (int r = 0; r < 8; r++) {
      float inv = __builtin_amdgcn_rcpf(bcast63(s[r]));
      float4 kv = *(const float4*)&kxv[pbase + 8 * g + r][0];
      float wf1 = inv * kv.x, wf2 = inv * kv.y, wf3 = inv * kv.z;
      float wv0 = kv.w * inv;
      float wv1 = kv.w * wf1, wv2 = kv.w * wf2, wv3 = kv.w * wf3;
      acc4(Tf0, inv, cur[r]);
      acc4(Tf1, wf1, cur[r]);
      acc4(Tf2, wf2, cur[r]);
      acc4(Tf3, wf3, cur[r]);
      acc4(Tv0, wv0, cur[r]);
      acc4(Tv1, wv1, cur[r]);
      acc4(Tv2, wv2, cur[r]);
      acc4(Tv3, wv3, cur[r]);
    }
#pragma unroll
    for (int r = 0; r < 8; r++) cur[r] = nx[r];
  }

  // epilogue dots: contract T accumulators with the A columns this lane owns
  float acc[24];
  {
    float4 a6[6];
#pragma unroll
    for (int k = 0; k < 6; k++) a6[k] = *(const float4*)&Af[k][j0];
#pragma unroll
    for (int e = 0; e < 3; e++) {
      acc[0 + e]  = dot4(Tv1, a6[e]);      // P_v row d=0
      acc[3 + e]  = dot4(Tv2, a6[e]);      // P_v row d=1
      acc[6 + e]  = dot4(Tv3, a6[e]);      // P_v row d=2
      acc[9 + e]  = dot4(Tf1, a6[3 + e]);  // P_f row d=0
      acc[12 + e] = dot4(Tf2, a6[3 + e]);  // P_f row d=1
      acc[15 + e] = dot4(Tf3, a6[3 + e]);  // P_f row d=2
      acc[18 + e] = dot4(Tv0, a6[e]);      // Sc
      acc[21 + e] = dot4(Tf0, a6[3 + e]);  // Scf
    }
  }
  // 24 independent DPP reduction chains
#pragma unroll
  for (int k = 0; k < 24; k++) acc[k] = dpp_red63(acc[k]);
  if (lane == 63) {
#pragma unroll
    for (int k = 0; k < 24; k++) atomicAdd(&bacc[k], acc[k]);
  }
  __syncthreads();

  if (t == 0) {
    float M = bacc[30];
    float Minv = 1.f / fmaxf(M, 1.f);
    bool use_v = (M > 3.f);
    const float Ninv = 1.f / (float)BN;
    float H[3][3], mu[3];
#pragma unroll
    for (int d = 0; d < 3; d++) {
      mu[d] = use_v ? bacc[24 + d] * Minv : bacc[27 + d] * Ninv;
#pragma unroll
      for (int e = 0; e < 3; e++) {
        float hv = bacc[d * 3 + e]     - bacc[24 + d] * bacc[18 + e] * Minv;
        float hf = bacc[9 + d * 3 + e] - bacc[27 + d] * bacc[21 + e] * Ninv;
        H[d][e] = use_v ? hv : hf;
      }
    }
    float K[3][3];
#pragma unroll
    for (int i = 0; i < 3; i++)
#pragma unroll
      for (int j = 0; j < 3; j++) {
        float s_ = 0.f;
#pragma unroll
        for (int k = 0; k < 3; k++) s_ += H[k][i] * H[k][j];
        K[i][j] = s_;
      }
    float V[3][3] = {{1.f,0.f,0.f},{0.f,1.f,0.f},{0.f,0.f,1.f}};
    for (int sw = 0; sw < 8; sw++) { jrot<0,1>(K, V); jrot<0,2>(K, V); jrot<1,2>(K, V); }
    float lam[3] = {K[0][0], K[1][1], K[2][2]};
    cswap<0,1>(lam, V); cswap<1,2>(lam, V); cswap<0,1>(lam, V);

    float v1[3] = {V[0][0], V[1][0], V[2][0]};
    float v2[3] = {V[0][1], V[1][1], V[2][1]};
    float v3[3] = {V[0][2], V[1][2], V[2][2]};
    float u1[3], u2[3], u3[3];
#pragma unroll
    for (int i = 0; i < 3; i++) {
      u1[i] = H[i][0] * v1[0] + H[i][1] * v1[1] + H[i][2] * v1[2];
      u2[i] = H[i][0] * v2[0] + H[i][1] * v2[1] + H[i][2] * v2[2];
    }
    float n1s = u1[0]*u1[0] + u1[1]*u1[1] + u1[2]*u1[2];
    if (n1s > 1e-24f) { float r = 1.f / sqrtf(n1s); u1[0]*=r; u1[1]*=r; u1[2]*=r; }
    else { u1[0] = 1.f; u1[1] = 0.f; u1[2] = 0.f; }
    float d12 = u1[0]*u2[0] + u1[1]*u2[1] + u1[2]*u2[2];
    u2[0] -= d12 * u1[0]; u2[1] -= d12 * u1[1]; u2[2] -= d12 * u1[2];
    float n2s = u2[0]*u2[0] + u2[1]*u2[1] + u2[2]*u2[2];
    if (n2s > 1e-24f) { float r = 1.f / sqrtf(n2s); u2[0]*=r; u2[1]*=r; u2[2]*=r; }
    else {
      float ex_ = (fabsf(u1[0]) < 0.9f) ? 1.f : 0.f;
      float ey = 1.f - ex_;
      float cx = u1[1]*0.f - u1[2]*ey;
      float cy = u1[2]*ex_ - u1[0]*0.f;
      float cz = u1[0]*ey - u1[1]*ex_;
      float nn = 1.f / sqrtf(cx*cx + cy*cy + cz*cz + 1e-30f);
      u2[0] = cx*nn; u2[1] = cy*nn; u2[2] = cz*nn;
    }
    u3[0] = u1[1]*u2[2] - u1[2]*u2[1];
    u3[1] = u1[2]*u2[0] - u1[0]*u2[2];
    u3[2] = u1[0]*u2[1] - u1[1]*u2[0];
    float detV = v1[0]*(v2[1]*v3[2] - v2[2]*v3[1])
               - v1[1]*(v2[0]*v3[2] - v2[2]*v3[0])
               + v1[2]*(v2[0]*v3[1] - v2[1]*v3[0]);
    float f = (detV < 0.f) ? -1.f : 1.f;
    float R_[3][3];
#pragma unroll
    for (int i = 0; i < 3; i++)
#pragma unroll
      for (int k = 0; k < 3; k++)
        R_[i][k] = v1[i]*u1[k] + v2[i]*u2[k] + f * v3[i]*u3[k];

    float* Rout = out + (size_t)b * 9;
#pragma unroll
    for (int i = 0; i < 3; i++)
#pragma unroll
      for (int k = 0; k < 3; k++)
        Rout[i * 3 + k] = R_[i][k];
    float* Tout = out + (size_t)gridDim.x * 9 + (size_t)b * 3;
#pragma unroll
    for (int i = 0; i < 3; i++)
      Tout[i] = -(R_[i][0]*mu[0] + R_[i][1]*mu[1] + R_[i][2]*mu[2]);
  }
}

extern "C" void kernel_launch(void* const* d_in, const int* in_sizes, int n_in,
                              void* d_out, int out_size, void* d_ws, size_t ws_size,
                              hipStream_t stream) {
  const float* src = (const float*)d_in[0];
  const float* tgt = (const float*)d_in[1];
  const float* scores = (const float*)d_in[2];
  const int* idx0 = (const int*)d_in[3];
  float* out = (float*)d_out;
  int B = in_sizes[0] / (3 * BN);
  hipLaunchKernelGGL(svdhead_kernel, dim3(B), dim3(BLOCK), 0, stream,
                     src, tgt, scores, idx0, out);
}